// Round 1
// baseline (799.854 us; speedup 1.0000x reference)
//
#include <hip/hip_runtime.h>

#define NB 8192
#define NT 512

typedef unsigned int u32;
typedef unsigned short u16;

__device__ __forceinline__ float rcp_(float x){ return __builtin_amdgcn_rcpf(x); }
__device__ __forceinline__ float exp2_(float x){ return __builtin_amdgcn_exp2f(x); }
// sigmoid(x) = 1/(1+2^(-x*log2e));  tanh(x) = 1 - 2/(1+2^(2x*log2e)).
// Both saturate correctly for |x| large (exp2 -> inf -> rcp -> 0).
__device__ __forceinline__ float sigm(float x){ return rcp_(1.0f + exp2_(-1.44269504088896341f * x)); }
__device__ __forceinline__ float tanh_(float x){ return 1.0f - 2.0f * rcp_(1.0f + exp2_(2.88539008177792681f * x)); }

__device__ __forceinline__ u32 packh2(float a, float b){
    _Float16 ha = (_Float16)a, hb = (_Float16)b;
    u16 lo, hi; __builtin_memcpy(&lo,&ha,2); __builtin_memcpy(&hi,&hb,2);
    return (u32)lo | ((u32)hi<<16);
}
__device__ __forceinline__ u16 packh1(float a){ _Float16 h=(_Float16)a; u16 r; __builtin_memcpy(&r,&h,2); return r; }
__device__ __forceinline__ float upkh(u16 v){ _Float16 h; __builtin_memcpy(&h,&v,2); return (float)h; }
__device__ __forceinline__ float upk_lo(u32 v){ return upkh((u16)(v&0xffffu)); }
__device__ __forceinline__ float upk_hi(u32 v){ return upkh((u16)(v>>16)); }

// ---------------------------------------------------------------------------
// Layer 0, both directions. 2 lanes per sequence: lane q owns hidden indices
// j in {3q,3q+1,3q+2} of all 4 gates. Stores h as fp16 into l0 buffer.
// Per-element slot encoding (12 bytes per direction):
//   dword@0  = (h0,h1) written by lane 0      dword@4 = (h3,h4) by lane 1
//   ushort@8 = h2 by lane 0                   ushort@10 = h5 by lane 1
// STORE_FWD=1: both dirs, elem stride 24B (fwd at +0, bwd at +12)
// STORE_FWD=0: only bwd launched, elem stride 12B
// ---------------------------------------------------------------------------
template<int STORE_FWD>
__global__ __launch_bounds__(64,1) void lstm_l0(
    const float* __restrict__ x,
    const float* __restrict__ h0, const float* __restrict__ c0,
    const float* __restrict__ Wihf, const float* __restrict__ Whhf, const float* __restrict__ bf,
    const float* __restrict__ Wihb, const float* __restrict__ Whhb, const float* __restrict__ bb,
    char* __restrict__ obuf)
{
    const int tid = blockIdx.x*64 + threadIdx.x;
    const int q   = tid & 1;
    const int e   = tid >> 1;
    const int b   = e & (NB-1);
    const int dir = STORE_FWD ? (e >> 13) : 1;
    const int ESTRIDE = STORE_FWD ? 24 : 12;

    const float* Wih = dir ? Wihb : Wihf;
    const float* Whh = dir ? Whhb : Whhf;
    const float* bia = dir ? bb  : bf;

    // rows handled by this lane: r = g*6 + 3q + i  (g = gate i,f,g,o ; i = 0..2)
    float Wx[4][3][6], Uo[4][3][3], Ux[4][3][3], bz[4][3];
#pragma unroll
    for (int g=0; g<4; ++g)
#pragma unroll
    for (int i=0; i<3; ++i) {
        const int r = g*6 + 3*q + i;
        bz[g][i] = bia[r];
#pragma unroll
        for (int k=0;k<6;++k) Wx[g][i][k] = Wih[r*6+k];
#pragma unroll
        for (int k=0;k<3;++k){ Uo[g][i][k] = Whh[r*6+3*q+k]; Ux[g][i][k] = Whh[r*6+3*(1-q)+k]; }
    }

    float ho[3], hx[3], cc[3];
    {
        const int hb = dir*(NB*6) + b*6;
#pragma unroll
        for (int i=0;i<3;++i){
            ho[i] = h0[hb+3*q+i];
            hx[i] = h0[hb+3*(1-q)+i];
            cc[i] = c0[hb+3*q+i];
        }
    }

    const float* xb = x + (size_t)b*(NT*6);
    const int dt = dir ? -1 : 1;
    int t = dir ? (NT-1) : 0;

    float xv[6];
    {
        const float2* p = (const float2*)(xb + t*6);
        float2 a=p[0], d=p[1], f=p[2];
        xv[0]=a.x; xv[1]=a.y; xv[2]=d.x; xv[3]=d.y; xv[4]=f.x; xv[5]=f.y;
    }

    char* ob = obuf + (size_t)b*ESTRIDE + (STORE_FWD ? dir*12 : 0);
    const size_t tstr = (size_t)NB*ESTRIDE;

    for (int s=0; s<NT; ++s) {
        const int tn = t + dt;
        const int tp = (s==NT-1) ? t : tn;       // clamped prefetch index
        float xn[6];
        {
            const float2* p = (const float2*)(xb + tp*6);
            float2 a=p[0], d=p[1], f=p[2];
            xn[0]=a.x; xn[1]=a.y; xn[2]=d.x; xn[3]=d.y; xn[4]=f.x; xn[5]=f.y;
        }

        float z[4][3];
#pragma unroll
        for (int g=0; g<4; ++g)
#pragma unroll
        for (int i=0; i<3; ++i) {
            float acc = bz[g][i];
#pragma unroll
            for (int k=0;k<6;++k) acc = fmaf(Wx[g][i][k], xv[k], acc);
#pragma unroll
            for (int k=0;k<3;++k){
                acc = fmaf(Uo[g][i][k], ho[k], acc);
                acc = fmaf(Ux[g][i][k], hx[k], acc);
            }
            z[g][i] = acc;
        }

#pragma unroll
        for (int i=0;i<3;++i){
            const float ig = sigm(z[0][i]);
            const float fg = sigm(z[1][i]);
            const float gg = tanh_(z[2][i]);
            const float og = sigm(z[3][i]);
            cc[i] = fmaf(fg, cc[i], ig*gg);
            ho[i] = og * tanh_(cc[i]);
        }
#pragma unroll
        for (int i=0;i<3;++i) hx[i] = __shfl_xor(ho[i], 1);

        char* op = ob + (size_t)t*tstr;
        *(u32*)(op + 4*q)     = packh2(ho[0], ho[1]);
        *(u16*)(op + 8 + 2*q) = packh1(ho[2]);

        t = tn;
#pragma unroll
        for (int i=0;i<6;++i) xv[i] = xn[i];
    }
}

// ---------------------------------------------------------------------------
// Layer 1 forward scan over stored l0 (fp16), plus single r1 step and FC head.
// 2 lanes per sequence, same j-split.
// ---------------------------------------------------------------------------
__global__ __launch_bounds__(64,1) void lstm_l1_full(
    const char* __restrict__ l0buf,
    const float* __restrict__ h0, const float* __restrict__ c0,
    const float* __restrict__ W1f, const float* __restrict__ U1f, const float* __restrict__ b1fv,
    const float* __restrict__ W1b, const float* __restrict__ U1b, const float* __restrict__ b1bv,
    const float* __restrict__ fcw, const float* __restrict__ fcb,
    float* __restrict__ out)
{
    const int tid = blockIdx.x*64 + threadIdx.x;
    const int q = tid & 1;
    const int b = tid >> 1;

    float Wx[4][3][12], Uo[4][3][3], Ux[4][3][3], bz[4][3];
#pragma unroll
    for (int g=0; g<4; ++g)
#pragma unroll
    for (int i=0; i<3; ++i) {
        const int r = g*6 + 3*q + i;
        bz[g][i] = b1fv[r];
#pragma unroll
        for (int k=0;k<12;++k) Wx[g][i][k] = W1f[r*12+k];
#pragma unroll
        for (int k=0;k<3;++k){ Uo[g][i][k] = U1f[r*6+3*q+k]; Ux[g][i][k] = U1f[r*6+3*(1-q)+k]; }
    }

    float ho[3], hx[3], cc[3];
    {
        const int hb = 2*(NB*6) + b*6;   // layer-1 forward init = index 2
#pragma unroll
        for (int i=0;i<3;++i){
            ho[i] = h0[hb+3*q+i];
            hx[i] = h0[hb+3*(1-q)+i];
            cc[i] = c0[hb+3*q+i];
        }
    }

    const char* ib = l0buf + (size_t)b*24;
    const size_t tstr = (size_t)NB*24;

    float cur[12], nxt[12];
    auto ld = [&](int t, float* dst){
        const u32* p = (const u32*)(ib + (size_t)t*tstr);
        const u32 d0=p[0], d1=p[1], d2=p[2], d3=p[3], d4=p[4], d5=p[5];
        dst[0]=upk_lo(d0); dst[1]=upk_hi(d0); dst[2]=upk_lo(d2);
        dst[3]=upk_lo(d1); dst[4]=upk_hi(d1); dst[5]=upk_hi(d2);
        dst[6]=upk_lo(d3); dst[7]=upk_hi(d3); dst[8]=upk_lo(d5);
        dst[9]=upk_lo(d4); dst[10]=upk_hi(d4); dst[11]=upk_hi(d5);
    };
    ld(0, cur);

    for (int t=0; t<NT; ++t) {
        ld(t==NT-1 ? t : t+1, nxt);

        float z[4][3];
#pragma unroll
        for (int g=0; g<4; ++g)
#pragma unroll
        for (int i=0; i<3; ++i) {
            float acc = bz[g][i];
#pragma unroll
            for (int k=0;k<12;++k) acc = fmaf(Wx[g][i][k], cur[k], acc);
#pragma unroll
            for (int k=0;k<3;++k){
                acc = fmaf(Uo[g][i][k], ho[k], acc);
                acc = fmaf(Ux[g][i][k], hx[k], acc);
            }
            z[g][i] = acc;
        }
#pragma unroll
        for (int i=0;i<3;++i){
            const float ig = sigm(z[0][i]);
            const float fg = sigm(z[1][i]);
            const float gg = tanh_(z[2][i]);
            const float og = sigm(z[3][i]);
            cc[i] = fmaf(fg, cc[i], ig*gg);
            ho[i] = og * tanh_(cc[i]);
        }
#pragma unroll
        for (int i=0;i<3;++i) hx[i] = __shfl_xor(ho[i], 1);

        if (t < NT-1) {
#pragma unroll
            for (int k=0;k<12;++k) cur[k] = nxt[k];
        }
    }
    // Here: cur == l0[T-1] (logical order: f0[0..5], r0[0..5]); (ho,hx) == f1[T-1].

    // ---- r1: single reverse-direction step at t = T-1 ----
    float hr[6];
    {
        const int hb = 3*(NB*6) + b*6;
#pragma unroll
        for (int j=0;j<6;++j) hr[j] = h0[hb+j];
    }
    float cr[3];
    {
        const int hb = 3*(NB*6) + b*6;
#pragma unroll
        for (int i=0;i<3;++i) cr[i] = c0[hb+3*q+i];
    }
    float hro[3], hrx[3];
#pragma unroll
    for (int i=0;i<3;++i) {
        float zg[4];
#pragma unroll
        for (int g=0; g<4; ++g) {
            const int r = g*6 + 3*q + i;
            float acc = b1bv[r];
#pragma unroll
            for (int k=0;k<12;++k) acc = fmaf(W1b[r*12+k], cur[k], acc);
#pragma unroll
            for (int j=0;j<6;++j)  acc = fmaf(U1b[r*6+j], hr[j], acc);
            zg[g] = acc;
        }
        const float ig = sigm(zg[0]);
        const float fg = sigm(zg[1]);
        const float gg = tanh_(zg[2]);
        const float og = sigm(zg[3]);
        cr[i] = fmaf(fg, cr[i], ig*gg);
        hro[i] = og * tanh_(cr[i]);
    }
#pragma unroll
    for (int i=0;i<3;++i) hrx[i] = __shfl_xor(hro[i], 1);

    // ---- head: out[b][3q+i] = fcb + fcw . relu([f1, r1]) ----
    float ao[3], ax[3], po[3], px[3];
#pragma unroll
    for (int i=0;i<3;++i){
        ao[i] = fmaxf(ho[i], 0.f);
        ax[i] = fmaxf(hx[i], 0.f);
        po[i] = fmaxf(hro[i], 0.f);
        px[i] = fmaxf(hrx[i], 0.f);
    }
#pragma unroll
    for (int i=0;i<3;++i){
        const int r = 3*q + i;
        float acc = fcb[r];
#pragma unroll
        for (int k=0;k<3;++k){
            acc = fmaf(fcw[r*12 + 3*q + k],         ao[k], acc);
            acc = fmaf(fcw[r*12 + 3*(1-q) + k],     ax[k], acc);
            acc = fmaf(fcw[r*12 + 6 + 3*q + k],     po[k], acc);
            acc = fmaf(fcw[r*12 + 6 + 3*(1-q) + k], px[k], acc);
        }
        out[b*6 + r] = acc;
    }
}

// ---------------------------------------------------------------------------
// Fallback (small ws): f0 recomputed here alongside f1; only r0 was stored.
// ---------------------------------------------------------------------------
__global__ __launch_bounds__(64,1) void lstm_l1_rec(
    const char* __restrict__ r0buf,
    const float* __restrict__ x,
    const float* __restrict__ h0, const float* __restrict__ c0,
    const float* __restrict__ W0f, const float* __restrict__ U0f, const float* __restrict__ b0fv,
    const float* __restrict__ W1f, const float* __restrict__ U1f, const float* __restrict__ b1fv,
    const float* __restrict__ W1b, const float* __restrict__ U1b, const float* __restrict__ b1bv,
    const float* __restrict__ fcw, const float* __restrict__ fcb,
    float* __restrict__ out)
{
    const int tid = blockIdx.x*64 + threadIdx.x;
    const int q = tid & 1;
    const int b = tid >> 1;

    float W0[4][3][6], U0o[4][3][3], U0x[4][3][3], bz0[4][3];
    float W1[4][3][12], U1o[4][3][3], U1x[4][3][3], bz1[4][3];
#pragma unroll
    for (int g=0; g<4; ++g)
#pragma unroll
    for (int i=0; i<3; ++i) {
        const int r = g*6 + 3*q + i;
        bz0[g][i] = b0fv[r];
#pragma unroll
        for (int k=0;k<6;++k) W0[g][i][k] = W0f[r*6+k];
#pragma unroll
        for (int k=0;k<3;++k){ U0o[g][i][k] = U0f[r*6+3*q+k]; U0x[g][i][k] = U0f[r*6+3*(1-q)+k]; }
        bz1[g][i] = b1fv[r];
        // columns pre-permuted: c<3 -> f0 own strip; 3<=c<6 -> f0 other strip; c>=6 -> r0
#pragma unroll
        for (int c=0;c<12;++c){
            const int k = (c<3) ? (3*q+c) : (c<6 ? (3*(1-q)+(c-3)) : c);
            W1[g][i][c] = W1f[r*12+k];
        }
#pragma unroll
        for (int k=0;k<3;++k){ U1o[g][i][k] = U1f[r*6+3*q+k]; U1x[g][i][k] = U1f[r*6+3*(1-q)+k]; }
    }

    float h0o[3], h0x[3], cl0[3];
    float h1o[3], h1x[3], cl1[3];
    {
        const int hb0 = 0*(NB*6) + b*6;
        const int hb1 = 2*(NB*6) + b*6;
#pragma unroll
        for (int i=0;i<3;++i){
            h0o[i] = h0[hb0+3*q+i]; h0x[i] = h0[hb0+3*(1-q)+i]; cl0[i] = c0[hb0+3*q+i];
            h1o[i] = h0[hb1+3*q+i]; h1x[i] = h0[hb1+3*(1-q)+i]; cl1[i] = c0[hb1+3*q+i];
        }
    }

    const float* xb = x + (size_t)b*(NT*6);
    const char* rb = r0buf + (size_t)b*12;
    const size_t tstr = (size_t)NB*12;

    float xv[6], rv[6];
    {
        const float2* p = (const float2*)(xb);
        float2 a=p[0], d=p[1], f=p[2];
        xv[0]=a.x; xv[1]=a.y; xv[2]=d.x; xv[3]=d.y; xv[4]=f.x; xv[5]=f.y;
        const u32* rp = (const u32*)rb;
        const u32 d0=rp[0], d1=rp[1], d2=rp[2];
        rv[0]=upk_lo(d0); rv[1]=upk_hi(d0); rv[2]=upk_lo(d2);
        rv[3]=upk_lo(d1); rv[4]=upk_hi(d1); rv[5]=upk_hi(d2);
    }

    for (int t=0; t<NT; ++t) {
        const int tp = (t==NT-1) ? t : t+1;
        float xn[6], rn[6];
        {
            const float2* p = (const float2*)(xb + tp*6);
            float2 a=p[0], d=p[1], f=p[2];
            xn[0]=a.x; xn[1]=a.y; xn[2]=d.x; xn[3]=d.y; xn[4]=f.x; xn[5]=f.y;
            const u32* rp = (const u32*)(rb + (size_t)tp*tstr);
            const u32 d0=rp[0], d1=rp[1], d2=rp[2];
            rn[0]=upk_lo(d0); rn[1]=upk_hi(d0); rn[2]=upk_lo(d2);
            rn[3]=upk_lo(d1); rn[4]=upk_hi(d1); rn[5]=upk_hi(d2);
        }

        // layer-0 forward step
        {
            float z[4][3];
#pragma unroll
            for (int g=0; g<4; ++g)
#pragma unroll
            for (int i=0; i<3; ++i) {
                float acc = bz0[g][i];
#pragma unroll
                for (int k=0;k<6;++k) acc = fmaf(W0[g][i][k], xv[k], acc);
#pragma unroll
                for (int k=0;k<3;++k){ acc = fmaf(U0o[g][i][k], h0o[k], acc); acc = fmaf(U0x[g][i][k], h0x[k], acc); }
                z[g][i] = acc;
            }
#pragma unroll
            for (int i=0;i<3;++i){
                const float ig = sigm(z[0][i]);
                const float fg = sigm(z[1][i]);
                const float gg = tanh_(z[2][i]);
                const float og = sigm(z[3][i]);
                cl0[i] = fmaf(fg, cl0[i], ig*gg);
                h0o[i] = og * tanh_(cl0[i]);
            }
#pragma unroll
            for (int i=0;i<3;++i) h0x[i] = __shfl_xor(h0o[i], 1);
        }

        // layer-1 forward step
        {
            float inv[12];
#pragma unroll
            for (int i=0;i<3;++i){ inv[i]=h0o[i]; inv[3+i]=h0x[i]; }
#pragma unroll
            for (int k=0;k<6;++k) inv[6+k]=rv[k];
            float z[4][3];
#pragma unroll
            for (int g=0; g<4; ++g)
#pragma unroll
            for (int i=0; i<3; ++i) {
                float acc = bz1[g][i];
#pragma unroll
                for (int c=0;c<12;++c) acc = fmaf(W1[g][i][c], inv[c], acc);
#pragma unroll
                for (int k=0;k<3;++k){ acc = fmaf(U1o[g][i][k], h1o[k], acc); acc = fmaf(U1x[g][i][k], h1x[k], acc); }
                z[g][i] = acc;
            }
#pragma unroll
            for (int i=0;i<3;++i){
                const float ig = sigm(z[0][i]);
                const float fg = sigm(z[1][i]);
                const float gg = tanh_(z[2][i]);
                const float og = sigm(z[3][i]);
                cl1[i] = fmaf(fg, cl1[i], ig*gg);
                h1o[i] = og * tanh_(cl1[i]);
            }
#pragma unroll
            for (int i=0;i<3;++i) h1x[i] = __shfl_xor(h1o[i], 1);
        }

#pragma unroll
        for (int i=0;i<6;++i){ xv[i]=xn[i]; rv[i]=rn[i]; }
    }

    // ---- r1 single step at t=T-1; l0last = [f0: h0o/h0x strips, r0: rv] ----
    float hr[6];
    {
        const int hb = 3*(NB*6) + b*6;
#pragma unroll
        for (int j=0;j<6;++j) hr[j] = h0[hb+j];
    }
    float cr[3];
    {
        const int hb = 3*(NB*6) + b*6;
#pragma unroll
        for (int i=0;i<3;++i) cr[i] = c0[hb+3*q+i];
    }
    float hro[3], hrx[3];
#pragma unroll
    for (int i=0;i<3;++i) {
        float zg[4];
#pragma unroll
        for (int g=0; g<4; ++g) {
            const int r = g*6 + 3*q + i;
            float acc = b1bv[r];
#pragma unroll
            for (int k=0;k<3;++k){
                acc = fmaf(W1b[r*12 + 3*q + k],     h0o[k], acc);
                acc = fmaf(W1b[r*12 + 3*(1-q) + k], h0x[k], acc);
            }
#pragma unroll
            for (int k=0;k<6;++k) acc = fmaf(W1b[r*12 + 6 + k], rv[k], acc);
#pragma unroll
            for (int j=0;j<6;++j) acc = fmaf(U1b[r*6+j], hr[j], acc);
            zg[g] = acc;
        }
        const float ig = sigm(zg[0]);
        const float fg = sigm(zg[1]);
        const float gg = tanh_(zg[2]);
        const float og = sigm(zg[3]);
        cr[i] = fmaf(fg, cr[i], ig*gg);
        hro[i] = og * tanh_(cr[i]);
    }
#pragma unroll
    for (int i=0;i<3;++i) hrx[i] = __shfl_xor(hro[i], 1);

    float ao[3], ax[3], po[3], px[3];
#pragma unroll
    for (int i=0;i<3;++i){
        ao[i] = fmaxf(h1o[i], 0.f);
        ax[i] = fmaxf(h1x[i], 0.f);
        po[i] = fmaxf(hro[i], 0.f);
        px[i] = fmaxf(hrx[i], 0.f);
    }
#pragma unroll
    for (int i=0;i<3;++i){
        const int r = 3*q + i;
        float acc = fcb[r];
#pragma unroll
        for (int k=0;k<3;++k){
            acc = fmaf(fcw[r*12 + 3*q + k],         ao[k], acc);
            acc = fmaf(fcw[r*12 + 3*(1-q) + k],     ax[k], acc);
            acc = fmaf(fcw[r*12 + 6 + 3*q + k],     po[k], acc);
            acc = fmaf(fcw[r*12 + 6 + 3*(1-q) + k], px[k], acc);
        }
        out[b*6 + r] = acc;
    }
}

extern "C" void kernel_launch(void* const* d_in, const int* in_sizes, int n_in,
                              void* d_out, int out_size, void* d_ws, size_t ws_size,
                              hipStream_t stream)
{
    (void)in_sizes; (void)n_in; (void)out_size;
    const float* x    = (const float*)d_in[0];
    const float* h0   = (const float*)d_in[1];
    const float* c0   = (const float*)d_in[2];
    const float* W0f  = (const float*)d_in[3];
    const float* U0f  = (const float*)d_in[4];
    const float* b0f  = (const float*)d_in[5];
    const float* W0b  = (const float*)d_in[6];
    const float* U0b  = (const float*)d_in[7];
    const float* b0b  = (const float*)d_in[8];
    const float* W1f  = (const float*)d_in[9];
    const float* U1f  = (const float*)d_in[10];
    const float* b1f  = (const float*)d_in[11];
    const float* W1b  = (const float*)d_in[12];
    const float* U1b  = (const float*)d_in[13];
    const float* b1b  = (const float*)d_in[14];
    const float* fcw  = (const float*)d_in[15];
    const float* fcb  = (const float*)d_in[16];
    float* out = (float*)d_out;
    char* ws = (char*)d_ws;

    const size_t needFull = (size_t)NT*NB*24;   // 100.7 MB: f0+r0 fp16
    if (ws_size >= needFull) {
        lstm_l0<1><<<dim3(512), dim3(64), 0, stream>>>(x, h0, c0, W0f, U0f, b0f, W0b, U0b, b0b, ws);
        lstm_l1_full<<<dim3(256), dim3(64), 0, stream>>>(ws, h0, c0, W1f, U1f, b1f, W1b, U1b, b1b, fcw, fcb, out);
    } else {
        lstm_l0<0><<<dim3(256), dim3(64), 0, stream>>>(x, h0, c0, W0f, U0f, b0f, W0b, U0b, b0b, ws);
        lstm_l1_rec<<<dim3(256), dim3(64), 0, stream>>>(ws, x, h0, c0, W0f, U0f, b0f, W1f, U1f, b1f, W1b, U1b, b1b, fcw, fcb, out);
    }
}

// Round 2
// 478.075 us; speedup vs baseline: 1.6731x; 1.6731x over previous
//
#include <hip/hip_runtime.h>

#define NB 8192
#define NT 512

typedef unsigned int u32;
typedef unsigned short u16;

__device__ __forceinline__ float rcp_(float x){ return __builtin_amdgcn_rcpf(x); }
__device__ __forceinline__ float exp2_(float x){ return __builtin_amdgcn_exp2f(x); }
// tanh for the cell state: tanh(x) = 1 - 2/(1+exp2(x*2*log2e)); saturates correctly at +/-inf.
__device__ __forceinline__ float tanh_(float x){ return 1.0f - 2.0f * rcp_(1.0f + exp2_(2.88539008177792681f * x)); }

__device__ __forceinline__ u32 packh2(float a, float b){
    _Float16 ha = (_Float16)a, hb = (_Float16)b;
    u16 lo, hi; __builtin_memcpy(&lo,&ha,2); __builtin_memcpy(&hi,&hb,2);
    return (u32)lo | ((u32)hi<<16);
}
__device__ __forceinline__ u16 packh1(float a){ _Float16 h=(_Float16)a; u16 r; __builtin_memcpy(&r,&h,2); return r; }
__device__ __forceinline__ float upkh(u16 v){ _Float16 h; __builtin_memcpy(&h,&v,2); return (float)h; }
__device__ __forceinline__ float upk_lo(u32 v){ return upkh((u16)(v&0xffffu)); }
__device__ __forceinline__ float upk_hi(u32 v){ return upkh((u16)(v>>16)); }

// ---------------------------------------------------------------------------
// 8-lane-per-sequence layout:
//   q = lane & 7;  gate role g = q & 3  (0=i, 1=f, 2=g(tanh), 3=o);
//   hidden half m = q >> 2 (owns hidden indices 3m..3m+2).
// Each lane computes z for its 3 rows (r = g*6 + 3m + i), applies its own
// gate's activation uniformly via per-lane constants (tanh = 2*sigm(2x)-1),
// then a 3-round shfl exchange reassembles (i,f,g,o) per hidden index so every
// lane of the half-group carries replicated c[3] and h_own[3].
// Activation: a = cM * rcp(1 + exp2(cE*z)) + cB
//   sigmoid: cE=-log2e,  cM=1, cB=0 ;  tanh: cE=-2log2e, cM=2, cB=-1
// ---------------------------------------------------------------------------
__device__ __forceinline__ void combine8(const float a[3], float c[3], float ho[3],
                                         bool b1, bool b2){
#pragma unroll
    for (int i=0;i<3;++i){
        const float r1 = __shfl_xor(a[i], 1);
        const float lo = b1 ? r1 : a[i];      // i-hat (lanes 0,1) / g-hat (2,3)
        const float hi = b1 ? a[i] : r1;      // f-hat (0,1) / o-hat (2,3)
        const float r2 = __shfl_xor(lo, 2);
        const float r3 = __shfl_xor(hi, 2);
        const float iv = b2 ? r2 : lo;
        const float gv = b2 ? lo : r2;
        const float fv = b2 ? r3 : hi;
        const float ov = b2 ? hi : r3;
        c[i] = fmaf(fv, c[i], iv*gv);
        ho[i] = ov * tanh_(c[i]);
    }
}

__device__ __forceinline__ void load6(const float* p, float* dst){
    const float2* v = (const float2*)p;
    float2 a=v[0], b=v[1], c=v[2];
    dst[0]=a.x; dst[1]=a.y; dst[2]=b.x; dst[3]=b.y; dst[4]=c.x; dst[5]=c.y;
}

// ---------------------------------------------------------------------------
// Layer 0, both directions. 2048 blocks x 64 threads = 2048 waves (2/SIMD).
// Output slot per (seq): 24B, fwd at +0, bwd at +12:
//   dword@0=(h0,h1)  dword@4=(h3,h4)  u16@8=h2  u16@10=h5   (fp16)
// ---------------------------------------------------------------------------
__global__ __launch_bounds__(64,2) void lstm_l0_g8(
    const float* __restrict__ x,
    const float* __restrict__ h0, const float* __restrict__ c0,
    const float* __restrict__ Wf, const float* __restrict__ Uf, const float* __restrict__ bf,
    const float* __restrict__ Wb, const float* __restrict__ Ub, const float* __restrict__ bb,
    char* __restrict__ obuf)
{
    const int tid = blockIdx.x*64 + threadIdx.x;
    const int q   = tid & 7;
    const int e   = tid >> 3;         // 0..16383 (seq-dir)
    const int b   = e & (NB-1);
    const int dir = e >> 13;
    const int g   = q & 3;
    const int m   = q >> 2;
    const bool b1 = (q & 1) != 0;
    const bool b2 = (q & 2) != 0;

    const float* W  = dir ? Wb : Wf;
    const float* U  = dir ? Ub : Uf;
    const float* bi = dir ? bb : bf;

    const float cE = (g==2) ? -2.88539008177792681f : -1.44269504088896341f;
    const float cM = (g==2) ? 2.0f : 1.0f;
    const float cB = (g==2) ? -1.0f : 0.0f;

    float Wx[3][6], Uh[3][6], bz[3];
#pragma unroll
    for (int i=0;i<3;++i){
        const int r = g*6 + 3*m + i;
        bz[i] = bi[r];
#pragma unroll
        for (int k=0;k<6;++k) Wx[i][k] = W[r*6+k];
#pragma unroll
        for (int k=0;k<3;++k){ Uh[i][k] = U[r*6 + 3*m + k]; Uh[i][3+k] = U[r*6 + 3*(1-m) + k]; }
    }

    float ho[3], hx[3], cc[3];
    {
        const int base = dir*(NB*6) + b*6;
#pragma unroll
        for (int i=0;i<3;++i){
            ho[i] = h0[base + 3*m + i];
            hx[i] = h0[base + 3*(1-m) + i];
            cc[i] = c0[base + 3*m + i];
        }
    }

    const float* xb = x + (size_t)b*(NT*6);
    const int dt = dir ? -1 : 1;
    int t = dir ? (NT-1) : 0;

    float xv[6];
    load6(xb + t*6, xv);

    char* ob = obuf + (size_t)b*24 + dir*12;
    const size_t tstr = (size_t)NB*24;

    for (int s=0; s<NT; ++s){
        const int tn = t + dt;
        const int tp = (s==NT-1) ? t : tn;
        float xn[6];
        load6(xb + tp*6, xn);

        float a[3];
#pragma unroll
        for (int i=0;i<3;++i){
            float acc = bz[i];
#pragma unroll
            for (int k=0;k<6;++k) acc = fmaf(Wx[i][k], xv[k], acc);
#pragma unroll
            for (int k=0;k<3;++k){ acc = fmaf(Uh[i][k], ho[k], acc); acc = fmaf(Uh[i][3+k], hx[k], acc); }
            a[i] = fmaf(cM, rcp_(1.0f + exp2_(cE*acc)), cB);
        }

        combine8(a, cc, ho, b1, b2);
#pragma unroll
        for (int i=0;i<3;++i) hx[i] = __shfl_xor(ho[i], 4);

        if (g == 0){
            char* op = ob + (size_t)t*tstr;
            *(u32*)(op + 4*m)     = packh2(ho[0], ho[1]);
            *(u16*)(op + 8 + 2*m) = packh1(ho[2]);
        }

        t = tn;
#pragma unroll
        for (int i=0;i<6;++i) xv[i] = xn[i];
    }
}

// ---------------------------------------------------------------------------
// Layer 1 forward scan over stored l0 (fp16), + single r1 step + FC head.
// 1024 blocks x 64 threads = 1024 waves (4/CU). Depth-2 prefetch of l0 dwords.
// ---------------------------------------------------------------------------
__global__ __launch_bounds__(64,1) void lstm_l1_g8(
    const char* __restrict__ l0buf,
    const float* __restrict__ h0, const float* __restrict__ c0,
    const float* __restrict__ W1f, const float* __restrict__ U1f, const float* __restrict__ b1f,
    const float* __restrict__ W1b, const float* __restrict__ U1b, const float* __restrict__ b1b,
    const float* __restrict__ fcw, const float* __restrict__ fcb,
    float* __restrict__ out)
{
    const int tid = blockIdx.x*64 + threadIdx.x;
    const int q = tid & 7;
    const int b = tid >> 3;           // 0..8191
    const int g = q & 3;
    const int m = q >> 2;
    const bool b1 = (q & 1) != 0;
    const bool b2 = (q & 2) != 0;

    const float cE = (g==2) ? -2.88539008177792681f : -1.44269504088896341f;
    const float cM = (g==2) ? 2.0f : 1.0f;
    const float cB = (g==2) ? -1.0f : 0.0f;

    float Wx[3][12], Uh[3][6], bz[3];
#pragma unroll
    for (int i=0;i<3;++i){
        const int r = g*6 + 3*m + i;
        bz[i] = b1f[r];
#pragma unroll
        for (int k=0;k<12;++k) Wx[i][k] = W1f[r*12+k];
#pragma unroll
        for (int k=0;k<3;++k){ Uh[i][k] = U1f[r*6 + 3*m + k]; Uh[i][3+k] = U1f[r*6 + 3*(1-m) + k]; }
    }

    float ho[3], hx[3], cc[3];
    {
        const int base = 2*(NB*6) + b*6;
#pragma unroll
        for (int i=0;i<3;++i){
            ho[i] = h0[base + 3*m + i];
            hx[i] = h0[base + 3*(1-m) + i];
            cc[i] = c0[base + 3*m + i];
        }
    }

    const char* ib = l0buf + (size_t)b*24;
    const size_t tstr = (size_t)NB*24;

    u32 dA[6], dB[6];
    auto loadD = [&](int t, u32* d){
        const u32* p = (const u32*)(ib + (size_t)t*tstr);
#pragma unroll
        for (int k=0;k<6;++k) d[k] = p[k];
    };
    float in[12];
    auto unpack = [&](const u32* d){
        in[0]=upk_lo(d[0]); in[1]=upk_hi(d[0]); in[2]=upk_lo(d[2]);
        in[3]=upk_lo(d[1]); in[4]=upk_hi(d[1]); in[5]=upk_hi(d[2]);
        in[6]=upk_lo(d[3]); in[7]=upk_hi(d[3]); in[8]=upk_lo(d[5]);
        in[9]=upk_lo(d[4]); in[10]=upk_hi(d[4]); in[11]=upk_hi(d[5]);
    };
    auto step = [&](){
        float a[3];
#pragma unroll
        for (int i=0;i<3;++i){
            float acc = bz[i];
#pragma unroll
            for (int k=0;k<12;++k) acc = fmaf(Wx[i][k], in[k], acc);
#pragma unroll
            for (int k=0;k<3;++k){ acc = fmaf(Uh[i][k], ho[k], acc); acc = fmaf(Uh[i][3+k], hx[k], acc); }
            a[i] = fmaf(cM, rcp_(1.0f + exp2_(cE*acc)), cB);
        }
        combine8(a, cc, ho, b1, b2);
#pragma unroll
        for (int i=0;i<3;++i) hx[i] = __shfl_xor(ho[i], 4);
    };

    loadD(0, dA); loadD(1, dB);

    for (int t=0; t<NT; t+=2){
        unpack(dA);
        loadD(t+2 <= NT-1 ? t+2 : NT-1, dA);
        step();
        unpack(dB);
        loadD(t+3 <= NT-1 ? t+3 : NT-1, dB);
        step();
    }
    // now: in == l0[NT-1]; (ho,hx) == f1[NT-1]

    float f1o[3], f1x[3];
#pragma unroll
    for (int i=0;i<3;++i){ f1o[i]=ho[i]; f1x[i]=hx[i]; }

    // ---- r1: single reverse-direction step at t = NT-1 ----
    const int base3 = 3*(NB*6) + b*6;
    float hr[6];
#pragma unroll
    for (int j=0;j<6;++j) hr[j] = h0[base3 + j];
    float cr[3];
#pragma unroll
    for (int i=0;i<3;++i) cr[i] = c0[base3 + 3*m + i];

    float a[3];
#pragma unroll
    for (int i=0;i<3;++i){
        const int r = g*6 + 3*m + i;
        float acc = b1b[r];
#pragma unroll
        for (int k=0;k<12;++k) acc = fmaf(W1b[r*12+k], in[k], acc);
#pragma unroll
        for (int j=0;j<6;++j)  acc = fmaf(U1b[r*6+j], hr[j], acc);
        a[i] = fmaf(cM, rcp_(1.0f + exp2_(cE*acc)), cB);
    }
    float r1o[3];
    combine8(a, cr, r1o, b1, b2);
    float r1x[3];
#pragma unroll
    for (int i=0;i<3;++i) r1x[i] = __shfl_xor(r1o[i], 4);

    // ---- head (2 lanes per seq store 3 outputs each) ----
    if (g == 0){
#pragma unroll
        for (int i=0;i<3;++i){
            const int r = 3*m + i;
            float acc = fcb[r];
#pragma unroll
            for (int k=0;k<3;++k){
                acc = fmaf(fcw[r*12 + 3*m + k],         fmaxf(f1o[k],0.f), acc);
                acc = fmaf(fcw[r*12 + 3*(1-m) + k],     fmaxf(f1x[k],0.f), acc);
                acc = fmaf(fcw[r*12 + 6 + 3*m + k],     fmaxf(r1o[k],0.f), acc);
                acc = fmaf(fcw[r*12 + 6 + 3*(1-m) + k], fmaxf(r1x[k],0.f), acc);
            }
            out[b*6 + r] = acc;
        }
    }
}

extern "C" void kernel_launch(void* const* d_in, const int* in_sizes, int n_in,
                              void* d_out, int out_size, void* d_ws, size_t ws_size,
                              hipStream_t stream)
{
    (void)in_sizes; (void)n_in; (void)out_size; (void)ws_size;
    const float* x    = (const float*)d_in[0];
    const float* h0   = (const float*)d_in[1];
    const float* c0   = (const float*)d_in[2];
    const float* W0f  = (const float*)d_in[3];
    const float* U0f  = (const float*)d_in[4];
    const float* b0f  = (const float*)d_in[5];
    const float* W0b  = (const float*)d_in[6];
    const float* U0b  = (const float*)d_in[7];
    const float* b0b  = (const float*)d_in[8];
    const float* W1f  = (const float*)d_in[9];
    const float* U1f  = (const float*)d_in[10];
    const float* b1f  = (const float*)d_in[11];
    const float* W1b  = (const float*)d_in[12];
    const float* U1b  = (const float*)d_in[13];
    const float* b1b  = (const float*)d_in[14];
    const float* fcw  = (const float*)d_in[15];
    const float* fcb  = (const float*)d_in[16];
    float* out = (float*)d_out;
    char* ws = (char*)d_ws;

    lstm_l0_g8<<<dim3(2048), dim3(64), 0, stream>>>(x, h0, c0, W0f, U0f, b0f, W0b, U0b, b0b, ws);
    lstm_l1_g8<<<dim3(1024), dim3(64), 0, stream>>>(ws, h0, c0, W1f, U1f, b1f, W1b, U1b, b1b, fcw, fcb, out);
}

// Round 4
// 470.219 us; speedup vs baseline: 1.7010x; 1.0167x over previous
//
#include <hip/hip_runtime.h>

#define NB 8192
#define NT 512

typedef unsigned int u32;
typedef unsigned short u16;
typedef float f32x2 __attribute__((ext_vector_type(2)));
typedef _Float16 h16x2 __attribute__((ext_vector_type(2)));

__device__ __forceinline__ float rcp_(float x){ return __builtin_amdgcn_rcpf(x); }
__device__ __forceinline__ float exp2_(float x){ return __builtin_amdgcn_exp2f(x); }
// tanh(x) = 1 - 2/(1+exp2(2x*log2e)); saturates correctly at +/-inf.
__device__ __forceinline__ float tanh_(float x){ return 1.0f - 2.0f*rcp_(1.0f + exp2_(2.88539008177792681f*x)); }

// quad_perm DPP move (VALU, no LDS): ctrl = p0|p1<<2|p2<<4|p3<<6
#define QP_XOR1 0xB1   // [1,0,3,2]
#define QP_XOR2 0x4E   // [2,3,0,1]  (== rot2)
#define QP_ROT1 0x39   // [1,2,3,0]
#define QP_ROT3 0x93   // [3,0,1,2]
template<int C>
__device__ __forceinline__ float dppf(float x){
    return __int_as_float(__builtin_amdgcn_update_dpp(0, __float_as_int(x), C, 0xF, 0xF, true));
}
// lane ^ 4 exchange (crosses quads): ds_swizzle BitMode offset = (4<<10)|0x1F
__device__ __forceinline__ float swz4(float x){
    return __int_as_float(__builtin_amdgcn_ds_swizzle(__float_as_int(x), 0x101F));
}
__device__ __forceinline__ void pkfma(f32x2& acc, f32x2 a, f32x2 b){
    asm("v_pk_fma_f32 %0, %1, %2, %0" : "+v"(acc) : "v"(a), "v"(b));
}
__device__ __forceinline__ f32x2 pkmul(f32x2 a, f32x2 b){
    f32x2 d; asm("v_pk_mul_f32 %0, %1, %2" : "=v"(d) : "v"(a), "v"(b)); return d;
}

__device__ __forceinline__ float upkh(u16 v){ _Float16 h; __builtin_memcpy(&h,&v,2); return (float)h; }
__device__ __forceinline__ float upk_lo(u32 v){ return upkh((u16)(v&0xffffu)); }
__device__ __forceinline__ float upk_hi(u32 v){ return upkh((u16)(v>>16)); }

__device__ __forceinline__ float dot2f(h16x2 a, h16x2 b, float c){
#if __has_builtin(__builtin_amdgcn_fdot2)
    return __builtin_amdgcn_fdot2(a, b, c, false);
#else
    return fmaf((float)a.x, (float)b.x, fmaf((float)a.y, (float)b.y, c));
#endif
}

// ---------------------------------------------------------------------------
// 8-lane-per-sequence layout: q = lane&7; gate g = q&3 (0=i,1=f,2=g,3=o);
// hidden half m = q>>2 (owns indices 3m..3m+2).
// cell_update: gather the 4 gate activations per hidden index via quad DPP,
// update c, compute tanh(c) ONCE per lane (spread across the quad, gathered
// back via quad rotations), produce ho.
// ---------------------------------------------------------------------------
__device__ __forceinline__ void cell_update(const float a[3], float c[3], float ho[3], int g){
    const bool b1 = (g & 1) != 0;
    const bool b2 = (g & 2) != 0;
    float ov[3];
#pragma unroll
    for (int i=0;i<3;++i){
        const float r1 = dppf<QP_XOR1>(a[i]);
        const float lo = b1 ? r1 : a[i];
        const float hi = b1 ? a[i] : r1;
        const float r2 = dppf<QP_XOR2>(lo);
        const float r3 = dppf<QP_XOR2>(hi);
        const float iv = b2 ? r2 : lo;
        const float gv = b2 ? lo : r2;
        const float fv = b2 ? r3 : hi;
        ov[i]          = b2 ? hi : r3;
        c[i] = fmaf(fv, c[i], iv*gv);
    }
    // lane g computes tanh(c[g<3?g:0]); quad-rotations deliver all three.
    const float cg = (g==1) ? c[1] : ((g==2) ? c[2] : c[0]);
    const float tg = tanh_(cg);
    const float w1 = dppf<QP_ROT1>(tg);   // from lane (g+1)&3
    const float w2 = dppf<QP_XOR2>(tg);   // from lane (g+2)&3
    const float w3 = dppf<QP_ROT3>(tg);   // from lane (g+3)&3
#pragma unroll
    for (int j=0;j<3;++j){
        const int r = (j - g) & 3;        // source rotation distance
        const float lo = (r & 1) ? w1 : tg;
        const float hi = (r & 1) ? w3 : w2;
        ho[j] = ov[j] * ((r & 2) ? hi : lo);
    }
}

// ---------------------------------------------------------------------------
// Layer 0, both directions. 2048 waves (2/SIMD). Outputs fp16, separate
// fwd/bwd regions, 12B per (t,seq) slot:
//   dword@0=(h0,h1) [m=0], dword@4=(h3,h4) [m=1], u16@8=h2, u16@10=h5
// ---------------------------------------------------------------------------
__global__ __launch_bounds__(64,2) void lstm_l0_g8(
    const float* __restrict__ x,
    const float* __restrict__ h0, const float* __restrict__ c0,
    const float* __restrict__ Wf, const float* __restrict__ Uf, const float* __restrict__ bf,
    const float* __restrict__ Wb, const float* __restrict__ Ub, const float* __restrict__ bb,
    char* __restrict__ fbuf, char* __restrict__ bbuf)
{
    const int tid = blockIdx.x*64 + threadIdx.x;
    const int q   = tid & 7;
    const int e   = tid >> 3;
    const int b   = e & (NB-1);
    const int dir = e >> 13;
    const int g   = q & 3;
    const int m   = q >> 2;

    const float* W  = dir ? Wb : Wf;
    const float* U  = dir ? Ub : Uf;
    const float* bi = dir ? bb : bf;

    const float cE = (g==2) ? -2.88539008177792681f : -1.44269504088896341f;
    const float cM = (g==2) ? 2.0f : 1.0f;
    const float cB = (g==2) ? -1.0f : 0.0f;

    f32x2 Wx2[3][3], Uh2[3][3], bz2[3];
#pragma unroll
    for (int i=0;i<3;++i){
        const int r = g*6 + 3*m + i;
#pragma unroll
        for (int k=0;k<3;++k) Wx2[i][k] = f32x2{W[r*6+2*k], W[r*6+2*k+1]};
        Uh2[i][0] = f32x2{U[r*6+3*m+0],     U[r*6+3*m+1]};
        Uh2[i][1] = f32x2{U[r*6+3*m+2],     U[r*6+3*(1-m)+0]};
        Uh2[i][2] = f32x2{U[r*6+3*(1-m)+1], U[r*6+3*(1-m)+2]};
        bz2[i] = f32x2{bi[r], 0.0f};
    }

    float ho[3], hx[3], cc[3];
    {
        const int base = dir*(NB*6) + b*6;
#pragma unroll
        for (int i=0;i<3;++i){
            ho[i] = h0[base+3*m+i];
            hx[i] = h0[base+3*(1-m)+i];
            cc[i] = c0[base+3*m+i];
        }
    }

    const float* xb = x + (size_t)b*(NT*6);
    const int dt = dir ? -1 : 1;
    int t = dir ? (NT-1) : 0;

    const size_t tstr = (size_t)NB*12;
    char* op = (dir ? bbuf : fbuf) + (size_t)b*12 + (size_t)t*tstr;
    const ptrdiff_t dop = (ptrdiff_t)dt * (ptrdiff_t)tstr;

    f32x2 xA[3], xB[3];
    auto ldx = [&](int tt, f32x2* d){
        const f32x2* p = (const f32x2*)(xb + tt*6);
        d[0]=p[0]; d[1]=p[1]; d[2]=p[2];
    };
    ldx(t, xA); ldx(t+dt, xB);

    auto STEP = [&](f32x2* xv){
        f32x2 h2_0{ho[0],ho[1]}, h2_1{ho[2],hx[0]}, h2_2{hx[1],hx[2]};
        float a[3];
#pragma unroll
        for (int i=0;i<3;++i){
            f32x2 acc = bz2[i];
            pkfma(acc, Wx2[i][0], xv[0]);
            pkfma(acc, Wx2[i][1], xv[1]);
            pkfma(acc, Wx2[i][2], xv[2]);
            pkfma(acc, Uh2[i][0], h2_0);
            pkfma(acc, Uh2[i][1], h2_1);
            pkfma(acc, Uh2[i][2], h2_2);
            const float z = acc.x + acc.y;
            a[i] = fmaf(cM, rcp_(1.0f + exp2_(cE*z)), cB);
        }
        cell_update(a, cc, ho, g);
#pragma unroll
        for (int i=0;i<3;++i) hx[i] = swz4(ho[i]);
        if (g == 0){
            auto p01 = __builtin_amdgcn_cvt_pkrtz(ho[0], ho[1]);
            *(u32*)(op + 4*m) = __builtin_bit_cast(u32, p01);
            _Float16 h2v = (_Float16)ho[2];
            *(u16*)(op + 8 + 2*m) = __builtin_bit_cast(u16, h2v);
        }
    };

    for (int s=0; s<NT; s+=2){
        STEP(xA);
        { int tp = t + 2*dt; tp = tp<0?0:(tp>NT-1?NT-1:tp); ldx(tp, xA); }
        t += dt; op += dop;
        STEP(xB);
        { int tp = t + 2*dt; tp = tp<0?0:(tp>NT-1?NT-1:tp); ldx(tp, xB); }
        t += dt; op += dop;
    }
}

// ---------------------------------------------------------------------------
// Layer 1 forward scan (fp16 inputs consumed directly via v_dot2_f32_f16),
// + single r1 step + FC head. 1024 waves.
// ---------------------------------------------------------------------------
__global__ __launch_bounds__(64,1) void lstm_l1_g8(
    const char* __restrict__ fbuf, const char* __restrict__ bbuf,
    const float* __restrict__ h0, const float* __restrict__ c0,
    const float* __restrict__ W1f, const float* __restrict__ U1f, const float* __restrict__ b1f,
    const float* __restrict__ W1b, const float* __restrict__ U1b, const float* __restrict__ b1b,
    const float* __restrict__ fcw, const float* __restrict__ fcb,
    float* __restrict__ out)
{
    const int tid = blockIdx.x*64 + threadIdx.x;
    const int q = tid & 7;
    const int b = tid >> 3;
    const int g = q & 3;
    const int m = q >> 2;

    const float cE = (g==2) ? -2.88539008177792681f : -1.44269504088896341f;
    const float cM = (g==2) ? 2.0f : 1.0f;
    const float cB = (g==2) ? -1.0f : 0.0f;

    // fp16 weight pairs ordered to match the stored dwords:
    // fwd dwords: (c0,c1),(c3,c4),(c2,c5); bwd dwords: (c6,c7),(c9,c10),(c8,c11)
    h16x2 wh[3][6];
    f32x2 Uh2[3][3];
    float bz[3];
#pragma unroll
    for (int i=0;i<3;++i){
        const int r = g*6 + 3*m + i;
        const float* Wr = W1f + r*12;
#pragma unroll
        for (int k=0;k<6;++k){
            const int c0i = (k==0)?0:(k==1)?3:(k==2)?2:(k==3)?6:(k==4)?9:8;
            const int c1i = (k==0)?1:(k==1)?4:(k==2)?5:(k==3)?7:(k==4)?10:11;
            h16x2 v; v.x = (_Float16)Wr[c0i]; v.y = (_Float16)Wr[c1i];
            wh[i][k] = v;
        }
        Uh2[i][0] = f32x2{U1f[r*6+3*m+0],     U1f[r*6+3*m+1]};
        Uh2[i][1] = f32x2{U1f[r*6+3*m+2],     U1f[r*6+3*(1-m)+0]};
        Uh2[i][2] = f32x2{U1f[r*6+3*(1-m)+1], U1f[r*6+3*(1-m)+2]};
        bz[i] = b1f[r];
    }

    float ho[3], hx[3], cc[3];
    {
        const int base = 2*(NB*6) + b*6;
#pragma unroll
        for (int i=0;i<3;++i){
            ho[i] = h0[base+3*m+i];
            hx[i] = h0[base+3*(1-m)+i];
            cc[i] = c0[base+3*m+i];
        }
    }

    const char* pf = fbuf + (size_t)b*12;
    const char* pb = bbuf + (size_t)b*12;
    const size_t tstr = (size_t)NB*12;

    u32 dA[6], dB[6];
    auto loadD = [&](int tt, u32* d){
        const u32* f = (const u32*)(pf + (size_t)tt*tstr);
        const u32* r = (const u32*)(pb + (size_t)tt*tstr);
        d[0]=f[0]; d[1]=f[1]; d[2]=f[2]; d[3]=r[0]; d[4]=r[1]; d[5]=r[2];
    };

    auto STEP = [&](u32* d){
        f32x2 h2_0{ho[0],ho[1]}, h2_1{ho[2],hx[0]}, h2_2{hx[1],hx[2]};
        float a[3];
#pragma unroll
        for (int i=0;i<3;++i){
            float s = bz[i];
#pragma unroll
            for (int k=0;k<6;++k)
                s = dot2f(wh[i][k], __builtin_bit_cast(h16x2, d[k]), s);
            f32x2 acc = pkmul(Uh2[i][0], h2_0);
            pkfma(acc, Uh2[i][1], h2_1);
            pkfma(acc, Uh2[i][2], h2_2);
            const float z = s + acc.x + acc.y;
            a[i] = fmaf(cM, rcp_(1.0f + exp2_(cE*z)), cB);
        }
        cell_update(a, cc, ho, g);
#pragma unroll
        for (int i=0;i<3;++i) hx[i] = swz4(ho[i]);
    };

    loadD(0, dA); loadD(1, dB);
    for (int t=0; t<NT; t+=2){
        STEP(dA);
        { int tp = t+2; tp = tp>NT-1?NT-1:tp; loadD(tp, dA); }
        STEP(dB);
        { int tp = t+3; tp = tp>NT-1?NT-1:tp; loadD(tp, dB); }
    }
    // dB holds l0[NT-1]; (ho,hx) == f1[NT-1]

    float in[12];
    in[0]=upk_lo(dB[0]); in[1]=upk_hi(dB[0]); in[3]=upk_lo(dB[1]);
    in[4]=upk_hi(dB[1]); in[2]=upk_lo(dB[2]); in[5]=upk_hi(dB[2]);
    in[6]=upk_lo(dB[3]); in[7]=upk_hi(dB[3]); in[9]=upk_lo(dB[4]);
    in[10]=upk_hi(dB[4]); in[8]=upk_lo(dB[5]); in[11]=upk_hi(dB[5]);

    // ---- r1: single reverse-direction step at t = NT-1 ----
    const int base3 = 3*(NB*6) + b*6;
    float hr[6];
#pragma unroll
    for (int j=0;j<6;++j) hr[j] = h0[base3 + j];
    float cr[3];
#pragma unroll
    for (int i=0;i<3;++i) cr[i] = c0[base3 + 3*m + i];

    float a[3];
#pragma unroll
    for (int i=0;i<3;++i){
        const int r = g*6 + 3*m + i;
        float acc = b1b[r];
#pragma unroll
        for (int k=0;k<12;++k) acc = fmaf(W1b[r*12+k], in[k], acc);
#pragma unroll
        for (int j=0;j<6;++j)  acc = fmaf(U1b[r*6+j], hr[j], acc);
        a[i] = fmaf(cM, rcp_(1.0f + exp2_(cE*acc)), cB);
    }
    float r1o[3];
    cell_update(a, cr, r1o, g);
    float r1x[3];
#pragma unroll
    for (int i=0;i<3;++i) r1x[i] = swz4(r1o[i]);

    // ---- head ----
    if (g == 0){
#pragma unroll
        for (int i=0;i<3;++i){
            const int r = 3*m + i;
            float acc = fcb[r];
#pragma unroll
            for (int k=0;k<3;++k){
                acc = fmaf(fcw[r*12 + 3*m + k],         fmaxf(ho[k],0.f), acc);
                acc = fmaf(fcw[r*12 + 3*(1-m) + k],     fmaxf(hx[k],0.f), acc);
                acc = fmaf(fcw[r*12 + 6 + 3*m + k],     fmaxf(r1o[k],0.f), acc);
                acc = fmaf(fcw[r*12 + 6 + 3*(1-m) + k], fmaxf(r1x[k],0.f), acc);
            }
            out[b*6 + r] = acc;
        }
    }
}

extern "C" void kernel_launch(void* const* d_in, const int* in_sizes, int n_in,
                              void* d_out, int out_size, void* d_ws, size_t ws_size,
                              hipStream_t stream)
{
    (void)in_sizes; (void)n_in; (void)out_size; (void)ws_size;
    const float* x    = (const float*)d_in[0];
    const float* h0   = (const float*)d_in[1];
    const float* c0   = (const float*)d_in[2];
    const float* W0f  = (const float*)d_in[3];
    const float* U0f  = (const float*)d_in[4];
    const float* b0f  = (const float*)d_in[5];
    const float* W0b  = (const float*)d_in[6];
    const float* U0b  = (const float*)d_in[7];
    const float* b0b  = (const float*)d_in[8];
    const float* W1f  = (const float*)d_in[9];
    const float* U1f  = (const float*)d_in[10];
    const float* b1f  = (const float*)d_in[11];
    const float* W1b  = (const float*)d_in[12];
    const float* U1b  = (const float*)d_in[13];
    const float* b1b  = (const float*)d_in[14];
    const float* fcw  = (const float*)d_in[15];
    const float* fcb  = (const float*)d_in[16];
    float* out = (float*)d_out;
    char* ws = (char*)d_ws;

    char* fbuf = ws;
    char* bbuf = ws + (size_t)NT*NB*12;

    lstm_l0_g8<<<dim3(2048), dim3(64), 0, stream>>>(x, h0, c0, W0f, U0f, b0f, W0b, U0b, b0b, fbuf, bbuf);
    lstm_l1_g8<<<dim3(1024), dim3(64), 0, stream>>>(fbuf, bbuf, h0, c0, W1f, U1f, b1f, W1b, U1b, b1b, fcw, fcb, out);
}

// Round 5
// 458.125 us; speedup vs baseline: 1.7459x; 1.0264x over previous
//
#include <hip/hip_runtime.h>

#define NB 8192
#define NT 512

typedef unsigned int u32;
typedef unsigned short u16;
typedef float f32x2 __attribute__((ext_vector_type(2)));
typedef _Float16 h16x2 __attribute__((ext_vector_type(2)));

__device__ __forceinline__ float rcp_(float x){ return __builtin_amdgcn_rcpf(x); }
__device__ __forceinline__ float exp2_(float x){ return __builtin_amdgcn_exp2f(x); }
// tanh(x) = 1 - 2/(1+exp2(2x*log2e)); saturates correctly at +/-inf.
__device__ __forceinline__ float tanh_(float x){ return 1.0f - 2.0f*rcp_(1.0f + exp2_(2.88539008177792681f*x)); }

// Pin a value into a VGPR (defeats per-iteration rematerialization/reload).
#define PINF(v)  asm volatile("" : "+v"(v))

// quad_perm DPP move (VALU, no LDS): ctrl = p0|p1<<2|p2<<4|p3<<6
#define QP_XOR1 0xB1   // [1,0,3,2]
#define QP_XOR2 0x4E   // [2,3,0,1]  (== rot2)
#define QP_ROT1 0x39   // [1,2,3,0]
#define QP_ROT3 0x93   // [3,0,1,2]
template<int C>
__device__ __forceinline__ float dppf(float x){
    return __int_as_float(__builtin_amdgcn_update_dpp(0, __float_as_int(x), C, 0xF, 0xF, true));
}
// lane ^ 4 exchange (crosses quads): ds_swizzle BitMode offset = (4<<10)|0x1F
__device__ __forceinline__ float swz4(float x){
    return __int_as_float(__builtin_amdgcn_ds_swizzle(__float_as_int(x), 0x101F));
}
__device__ __forceinline__ void pkfma(f32x2& acc, f32x2 a, f32x2 b){
    asm("v_pk_fma_f32 %0, %1, %2, %0" : "+v"(acc) : "v"(a), "v"(b));
}
__device__ __forceinline__ f32x2 pkmul(f32x2 a, f32x2 b){
    f32x2 d; asm("v_pk_mul_f32 %0, %1, %2" : "=v"(d) : "v"(a), "v"(b)); return d;
}

__device__ __forceinline__ float upkh(u16 v){ _Float16 h; __builtin_memcpy(&h,&v,2); return (float)h; }
__device__ __forceinline__ float upk_lo(u32 v){ return upkh((u16)(v&0xffffu)); }
__device__ __forceinline__ float upk_hi(u32 v){ return upkh((u16)(v>>16)); }

__device__ __forceinline__ float dot2f(h16x2 a, h16x2 b, float c){
#if __has_builtin(__builtin_amdgcn_fdot2)
    return __builtin_amdgcn_fdot2(a, b, c, false);
#else
    return fmaf((float)a.x, (float)b.x, fmaf((float)a.y, (float)b.y, c));
#endif
}

// ---------------------------------------------------------------------------
// 8-lane-per-sequence layout: q = lane&7; gate g = q&3 (0=i,1=f,2=g,3=o);
// hidden half m = q>>2 (owns indices 3m..3m+2).
// ---------------------------------------------------------------------------
__device__ __forceinline__ void cell_update(const float a[3], float c[3], float ho[3], int g){
    const bool b1 = (g & 1) != 0;
    const bool b2 = (g & 2) != 0;
    float ov[3];
#pragma unroll
    for (int i=0;i<3;++i){
        const float r1 = dppf<QP_XOR1>(a[i]);
        const float lo = b1 ? r1 : a[i];
        const float hi = b1 ? a[i] : r1;
        const float r2 = dppf<QP_XOR2>(lo);
        const float r3 = dppf<QP_XOR2>(hi);
        const float iv = b2 ? r2 : lo;
        const float gv = b2 ? lo : r2;
        const float fv = b2 ? r3 : hi;
        ov[i]          = b2 ? hi : r3;
        c[i] = fmaf(fv, c[i], iv*gv);
    }
    // lane g computes tanh(c[g<3?g:0]); quad-rotations deliver all three.
    const float cg = (g==1) ? c[1] : ((g==2) ? c[2] : c[0]);
    const float tg = tanh_(cg);
    const float w1 = dppf<QP_ROT1>(tg);   // from lane (g+1)&3
    const float w2 = dppf<QP_XOR2>(tg);   // from lane (g+2)&3
    const float w3 = dppf<QP_ROT3>(tg);   // from lane (g+3)&3
#pragma unroll
    for (int j=0;j<3;++j){
        const int r = (j - g) & 3;        // source rotation distance
        const float lo = (r & 1) ? w1 : tg;
        const float hi = (r & 1) ? w3 : w2;
        ho[j] = ov[j] * ((r & 2) ? hi : lo);
    }
}

// ---------------------------------------------------------------------------
// Layer 0, both directions. 2048 waves (2/SIMD). Outputs fp16, separate
// fwd/bwd regions, 12B per (t,seq) slot:
//   dword@0=(h0,h1) [m=0], dword@4=(h3,h4) [m=1], u16@8=h2, u16@10=h5
// ---------------------------------------------------------------------------
__global__ __launch_bounds__(64,2) void lstm_l0_g8(
    const float* __restrict__ x,
    const float* __restrict__ h0, const float* __restrict__ c0,
    const float* __restrict__ Wf, const float* __restrict__ Uf, const float* __restrict__ bf,
    const float* __restrict__ Wb, const float* __restrict__ Ub, const float* __restrict__ bb,
    char* __restrict__ fbuf, char* __restrict__ bbuf)
{
    const int tid = blockIdx.x*64 + threadIdx.x;
    const int q   = tid & 7;
    const int e   = tid >> 3;
    const int b   = e & (NB-1);
    const int dir = e >> 13;
    const int g   = q & 3;
    const int m   = q >> 2;

    const float* W  = dir ? Wb : Wf;
    const float* U  = dir ? Ub : Uf;
    const float* bi = dir ? bb : bf;

    const float cE = (g==2) ? -2.88539008177792681f : -1.44269504088896341f;
    const float cM = (g==2) ? 2.0f : 1.0f;
    const float cB = (g==2) ? -1.0f : 0.0f;

    f32x2 Wx2[3][3], Uh2[3][3];
    float cEb[3];
#pragma unroll
    for (int i=0;i<3;++i){
        const int r = g*6 + 3*m + i;
#pragma unroll
        for (int k=0;k<3;++k) Wx2[i][k] = f32x2{W[r*6+2*k], W[r*6+2*k+1]};
        Uh2[i][0] = f32x2{U[r*6+3*m+0],     U[r*6+3*m+1]};
        Uh2[i][1] = f32x2{U[r*6+3*m+2],     U[r*6+3*(1-m)+0]};
        Uh2[i][2] = f32x2{U[r*6+3*(1-m)+1], U[r*6+3*(1-m)+2]};
        cEb[i] = cE * bi[r];
    }
    // Pin all loop-invariants into VGPRs (prevents per-step reloads).
#pragma unroll
    for (int i=0;i<3;++i){
#pragma unroll
        for (int k=0;k<3;++k){ PINF(Wx2[i][k]); PINF(Uh2[i][k]); }
        PINF(cEb[i]);
    }

    float ho[3], hx[3], cc[3];
    {
        const int base = dir*(NB*6) + b*6;
#pragma unroll
        for (int i=0;i<3;++i){
            ho[i] = h0[base+3*m+i];
            hx[i] = h0[base+3*(1-m)+i];
            cc[i] = c0[base+3*m+i];
        }
    }

    const float* xb = x + (size_t)b*(NT*6);
    const int dt = dir ? -1 : 1;
    int t = dir ? (NT-1) : 0;

    const size_t tstr = (size_t)NB*12;
    char* op = (dir ? bbuf : fbuf) + (size_t)b*12 + (size_t)t*tstr;
    const ptrdiff_t dop = (ptrdiff_t)dt * (ptrdiff_t)tstr;

    f32x2 xA[3], xB[3];
    auto ldx = [&](int tt, f32x2* d){
        const f32x2* p = (const f32x2*)(xb + tt*6);
        d[0]=p[0]; d[1]=p[1]; d[2]=p[2];
    };
    ldx(t, xA); ldx(t+dt, xB);

    auto STEP = [&](f32x2* xv){
        f32x2 h2_0{ho[0],ho[1]}, h2_1{ho[2],hx[0]}, h2_2{hx[1],hx[2]};
        float a[3];
#pragma unroll
        for (int i=0;i<3;++i){
            f32x2 acc = pkmul(Wx2[i][0], xv[0]);
            pkfma(acc, Wx2[i][1], xv[1]);
            pkfma(acc, Wx2[i][2], xv[2]);
            pkfma(acc, Uh2[i][0], h2_0);
            pkfma(acc, Uh2[i][1], h2_1);
            pkfma(acc, Uh2[i][2], h2_2);
            const float s = acc.x + acc.y;
            const float arg = fmaf(cE, s, cEb[i]);
            a[i] = fmaf(cM, rcp_(1.0f + exp2_(arg)), cB);
        }
        cell_update(a, cc, ho, g);
#pragma unroll
        for (int i=0;i<3;++i) hx[i] = swz4(ho[i]);
        if (g == 0){
            auto p01 = __builtin_amdgcn_cvt_pkrtz(ho[0], ho[1]);
            *(u32*)(op + 4*m) = __builtin_bit_cast(u32, p01);
            _Float16 h2v = (_Float16)ho[2];
            *(u16*)(op + 8 + 2*m) = __builtin_bit_cast(u16, h2v);
        }
    };

    for (int s=0; s<NT; s+=2){
        STEP(xA);
        { int tp = t + 2*dt; tp = tp<0?0:(tp>NT-1?NT-1:tp); ldx(tp, xA); }
        t += dt; op += dop;
        STEP(xB);
        { int tp = t + 2*dt; tp = tp<0?0:(tp>NT-1?NT-1:tp); ldx(tp, xB); }
        t += dt; op += dop;
    }
}

// ---------------------------------------------------------------------------
// Layer 1 forward scan (fp16 inputs consumed directly via v_dot2_f32_f16),
// + single r1 step + FC head. 1024 waves.
// ---------------------------------------------------------------------------
__global__ __launch_bounds__(64,1) void lstm_l1_g8(
    const char* __restrict__ fbuf, const char* __restrict__ bbuf,
    const float* __restrict__ h0, const float* __restrict__ c0,
    const float* __restrict__ W1f, const float* __restrict__ U1f, const float* __restrict__ b1f,
    const float* __restrict__ W1b, const float* __restrict__ U1b, const float* __restrict__ b1b,
    const float* __restrict__ fcw, const float* __restrict__ fcb,
    float* __restrict__ out)
{
    const int tid = blockIdx.x*64 + threadIdx.x;
    const int q = tid & 7;
    const int b = tid >> 3;
    const int g = q & 3;
    const int m = q >> 2;

    const float cE = (g==2) ? -2.88539008177792681f : -1.44269504088896341f;
    const float cM = (g==2) ? 2.0f : 1.0f;
    const float cB = (g==2) ? -1.0f : 0.0f;

    // fp16 weight pairs ordered to match the stored dwords:
    // fwd dwords: (c0,c1),(c3,c4),(c2,c5); bwd dwords: (c6,c7),(c9,c10),(c8,c11)
    h16x2 wh[3][6];
    f32x2 Uh2[3][3];
    float cEb[3];
#pragma unroll
    for (int i=0;i<3;++i){
        const int r = g*6 + 3*m + i;
        const float* Wr = W1f + r*12;
#pragma unroll
        for (int k=0;k<6;++k){
            const int c0i = (k==0)?0:(k==1)?3:(k==2)?2:(k==3)?6:(k==4)?9:8;
            const int c1i = (k==0)?1:(k==1)?4:(k==2)?5:(k==3)?7:(k==4)?10:11;
            h16x2 v; v.x = (_Float16)Wr[c0i]; v.y = (_Float16)Wr[c1i];
            wh[i][k] = v;
        }
        Uh2[i][0] = f32x2{U1f[r*6+3*m+0],     U1f[r*6+3*m+1]};
        Uh2[i][1] = f32x2{U1f[r*6+3*m+2],     U1f[r*6+3*(1-m)+0]};
        Uh2[i][2] = f32x2{U1f[r*6+3*(1-m)+1], U1f[r*6+3*(1-m)+2]};
        cEb[i] = cE * b1f[r];
    }
#pragma unroll
    for (int i=0;i<3;++i){
#pragma unroll
        for (int k=0;k<6;++k) PINF(wh[i][k]);
#pragma unroll
        for (int k=0;k<3;++k) PINF(Uh2[i][k]);
        PINF(cEb[i]);
    }

    float ho[3], hx[3], cc[3];
    {
        const int base = 2*(NB*6) + b*6;
#pragma unroll
        for (int i=0;i<3;++i){
            ho[i] = h0[base+3*m+i];
            hx[i] = h0[base+3*(1-m)+i];
            cc[i] = c0[base+3*m+i];
        }
    }

    const char* pf = fbuf + (size_t)b*12;
    const char* pb = bbuf + (size_t)b*12;
    const size_t tstr = (size_t)NB*12;

    u32 dA[6], dB[6];
    auto loadD = [&](int tt, u32* d){
        const u32* f = (const u32*)(pf + (size_t)tt*tstr);
        const u32* r = (const u32*)(pb + (size_t)tt*tstr);
        d[0]=f[0]; d[1]=f[1]; d[2]=f[2]; d[3]=r[0]; d[4]=r[1]; d[5]=r[2];
    };

    auto STEP = [&](u32* d){
        f32x2 h2_0{ho[0],ho[1]}, h2_1{ho[2],hx[0]}, h2_2{hx[1],hx[2]};
        float a[3];
#pragma unroll
        for (int i=0;i<3;++i){
            float s = dot2f(wh[i][0], __builtin_bit_cast(h16x2, d[0]), 0.0f);
#pragma unroll
            for (int k=1;k<6;++k)
                s = dot2f(wh[i][k], __builtin_bit_cast(h16x2, d[k]), s);
            f32x2 acc = pkmul(Uh2[i][0], h2_0);
            pkfma(acc, Uh2[i][1], h2_1);
            pkfma(acc, Uh2[i][2], h2_2);
            const float z = s + acc.x + acc.y;
            const float arg = fmaf(cE, z, cEb[i]);
            a[i] = fmaf(cM, rcp_(1.0f + exp2_(arg)), cB);
        }
        cell_update(a, cc, ho, g);
#pragma unroll
        for (int i=0;i<3;++i) hx[i] = swz4(ho[i]);
    };

    loadD(0, dA); loadD(1, dB);
    for (int t=0; t<NT; t+=2){
        STEP(dA);
        { int tp = t+2; tp = tp>NT-1?NT-1:tp; loadD(tp, dA); }
        STEP(dB);
        { int tp = t+3; tp = tp>NT-1?NT-1:tp; loadD(tp, dB); }
    }
    // dB holds l0[NT-1]; (ho,hx) == f1[NT-1]

    float in[12];
    in[0]=upk_lo(dB[0]); in[1]=upk_hi(dB[0]); in[3]=upk_lo(dB[1]);
    in[4]=upk_hi(dB[1]); in[2]=upk_lo(dB[2]); in[5]=upk_hi(dB[2]);
    in[6]=upk_lo(dB[3]); in[7]=upk_hi(dB[3]); in[9]=upk_lo(dB[4]);
    in[10]=upk_hi(dB[4]); in[8]=upk_lo(dB[5]); in[11]=upk_hi(dB[5]);

    // ---- r1: single reverse-direction step at t = NT-1 ----
    const int base3 = 3*(NB*6) + b*6;
    float hr[6];
#pragma unroll
    for (int j=0;j<6;++j) hr[j] = h0[base3 + j];
    float cr[3];
#pragma unroll
    for (int i=0;i<3;++i) cr[i] = c0[base3 + 3*m + i];

    float a[3];
#pragma unroll
    for (int i=0;i<3;++i){
        const int r = g*6 + 3*m + i;
        float acc = b1b[r];
#pragma unroll
        for (int k=0;k<12;++k) acc = fmaf(W1b[r*12+k], in[k], acc);
#pragma unroll
        for (int j=0;j<6;++j)  acc = fmaf(U1b[r*6+j], hr[j], acc);
        a[i] = fmaf(cM, rcp_(1.0f + exp2_(cE*acc)), cB);
    }
    float r1o[3];
    cell_update(a, cr, r1o, g);
    float r1x[3];
#pragma unroll
    for (int i=0;i<3;++i) r1x[i] = swz4(r1o[i]);

    // ---- head ----
    if (g == 0){
#pragma unroll
        for (int i=0;i<3;++i){
            const int r = 3*m + i;
            float acc = fcb[r];
#pragma unroll
            for (int k=0;k<3;++k){
                acc = fmaf(fcw[r*12 + 3*m + k],         fmaxf(ho[k],0.f), acc);
                acc = fmaf(fcw[r*12 + 3*(1-m) + k],     fmaxf(hx[k],0.f), acc);
                acc = fmaf(fcw[r*12 + 6 + 3*m + k],     fmaxf(r1o[k],0.f), acc);
                acc = fmaf(fcw[r*12 + 6 + 3*(1-m) + k], fmaxf(r1x[k],0.f), acc);
            }
            out[b*6 + r] = acc;
        }
    }
}

extern "C" void kernel_launch(void* const* d_in, const int* in_sizes, int n_in,
                              void* d_out, int out_size, void* d_ws, size_t ws_size,
                              hipStream_t stream)
{
    (void)in_sizes; (void)n_in; (void)out_size; (void)ws_size;
    const float* x    = (const float*)d_in[0];
    const float* h0   = (const float*)d_in[1];
    const float* c0   = (const float*)d_in[2];
    const float* W0f  = (const float*)d_in[3];
    const float* U0f  = (const float*)d_in[4];
    const float* b0f  = (const float*)d_in[5];
    const float* W0b  = (const float*)d_in[6];
    const float* U0b  = (const float*)d_in[7];
    const float* b0b  = (const float*)d_in[8];
    const float* W1f  = (const float*)d_in[9];
    const float* U1f  = (const float*)d_in[10];
    const float* b1f  = (const float*)d_in[11];
    const float* W1b  = (const float*)d_in[12];
    const float* U1b  = (const float*)d_in[13];
    const float* b1b  = (const float*)d_in[14];
    const float* fcw  = (const float*)d_in[15];
    const float* fcb  = (const float*)d_in[16];
    float* out = (float*)d_out;
    char* ws = (char*)d_ws;

    char* fbuf = ws;
    char* bbuf = ws + (size_t)NT*NB*12;

    lstm_l0_g8<<<dim3(2048), dim3(64), 0, stream>>>(x, h0, c0, W0f, U0f, b0f, W0b, U0b, b0b, fbuf, bbuf);
    lstm_l1_g8<<<dim3(1024), dim3(64), 0, stream>>>(fbuf, bbuf, h0, c0, W1f, U1f, b1f, W1b, U1b, b1b, fcw, fcb, out);
}

// Round 8
// 458.062 us; speedup vs baseline: 1.7462x; 1.0001x over previous
//
#include <hip/hip_runtime.h>

#define NB 8192
#define NT 512

typedef unsigned int u32;
typedef unsigned short u16;
typedef float f32x2 __attribute__((ext_vector_type(2)));
typedef _Float16 h16x2 __attribute__((ext_vector_type(2)));

__device__ __forceinline__ float rcp_(float x){ return __builtin_amdgcn_rcpf(x); }
__device__ __forceinline__ float exp2_(float x){ return __builtin_amdgcn_exp2f(x); }
// tanh(x) = 1 - 2/(1+exp2(2x*log2e)); saturates correctly at +/-inf.
__device__ __forceinline__ float tanh_(float x){ return 1.0f - 2.0f*rcp_(1.0f + exp2_(2.88539008177792681f*x)); }

// Pin a value into a VGPR (defeats per-iteration rematerialization/reload).
#define PINF(v)  asm volatile("" : "+v"(v))

// quad_perm DPP move (VALU, no LDS): ctrl = p0|p1<<2|p2<<4|p3<<6
#define QP_XOR1 0xB1   // [1,0,3,2]
#define QP_XOR2 0x4E   // [2,3,0,1]  (== rot2)
#define QP_ROT1 0x39   // [1,2,3,0]
#define QP_ROT3 0x93   // [3,0,1,2]
template<int C>
__device__ __forceinline__ float dppf(float x){
    return __int_as_float(__builtin_amdgcn_update_dpp(0, __float_as_int(x), C, 0xF, 0xF, true));
}
// lane ^ 4 exchange (crosses quads): ds_swizzle BitMode offset = (4<<10)|0x1F
// (known-good: validated in R4/R5 passing runs; the DPP row-shift variant
// had the shl/shr source-direction inverted and broke correctness in R6)
__device__ __forceinline__ float swz4(float x){
    return __int_as_float(__builtin_amdgcn_ds_swizzle(__float_as_int(x), 0x101F));
}
__device__ __forceinline__ void pkfma(f32x2& acc, f32x2 a, f32x2 b){
    asm("v_pk_fma_f32 %0, %1, %2, %0" : "+v"(acc) : "v"(a), "v"(b));
}
__device__ __forceinline__ f32x2 pkmul(f32x2 a, f32x2 b){
    f32x2 d; asm("v_pk_mul_f32 %0, %1, %2" : "=v"(d) : "v"(a), "v"(b)); return d;
}

__device__ __forceinline__ float upkh(u16 v){ _Float16 h; __builtin_memcpy(&h,&v,2); return (float)h; }
__device__ __forceinline__ float upk_lo(u32 v){ return upkh((u16)(v&0xffffu)); }
__device__ __forceinline__ float upk_hi(u32 v){ return upkh((u16)(v>>16)); }

__device__ __forceinline__ float dot2f(h16x2 a, h16x2 b, float c){
#if __has_builtin(__builtin_amdgcn_fdot2)
    return __builtin_amdgcn_fdot2(a, b, c, false);
#else
    return fmaf((float)a.x, (float)b.x, fmaf((float)a.y, (float)b.y, c));
#endif
}

// ---------------------------------------------------------------------------
// 8-lane-per-sequence layout: q = lane&7; gate g = q&3 (0=i,1=f,2=g,3=o);
// hidden half m = q>>2 (owns indices 3m..3m+2).
// ---------------------------------------------------------------------------
__device__ __forceinline__ void cell_update(const float a[3], float c[3], float ho[3], int g){
    const bool b1 = (g & 1) != 0;
    const bool b2 = (g & 2) != 0;
    float ov[3];
#pragma unroll
    for (int i=0;i<3;++i){
        const float r1 = dppf<QP_XOR1>(a[i]);
        const float lo = b1 ? r1 : a[i];
        const float hi = b1 ? a[i] : r1;
        const float r2 = dppf<QP_XOR2>(lo);
        const float r3 = dppf<QP_XOR2>(hi);
        const float iv = b2 ? r2 : lo;
        const float gv = b2 ? lo : r2;
        const float fv = b2 ? r3 : hi;
        ov[i]          = b2 ? hi : r3;
        c[i] = fmaf(fv, c[i], iv*gv);
    }
    // lane g computes tanh(c[g<3?g:0]); quad-rotations deliver all three.
    const float cg = (g==1) ? c[1] : ((g==2) ? c[2] : c[0]);
    const float tg = tanh_(cg);
    const float w1 = dppf<QP_ROT1>(tg);   // from lane (g+1)&3
    const float w2 = dppf<QP_XOR2>(tg);   // from lane (g+2)&3
    const float w3 = dppf<QP_ROT3>(tg);   // from lane (g+3)&3
#pragma unroll
    for (int j=0;j<3;++j){
        const int r = (j - g) & 3;        // source rotation distance
        const float lo = (r & 1) ? w1 : tg;
        const float hi = (r & 1) ? w3 : w2;
        ho[j] = ov[j] * ((r & 2) ? hi : lo);
    }
}

// ---------------------------------------------------------------------------
// Layer 0, both directions. 2048 waves (2/SIMD). Outputs fp16, separate
// fwd/bwd regions, 12B per (t,seq) slot:
//   dword@0=(h0,h1) [m=0], dword@4=(h3,h4) [m=1], u16@8=h2, u16@10=h5
// amdgpu_waves_per_eu(2,2): grid gives exactly 2 waves/SIMD; pin the
// allocator's occupancy target so weights stay register-resident.
// ---------------------------------------------------------------------------
__global__ __launch_bounds__(64)
__attribute__((amdgpu_waves_per_eu(2,2)))
void lstm_l0_g8(
    const float* __restrict__ x,
    const float* __restrict__ h0, const float* __restrict__ c0,
    const float* __restrict__ Wf, const float* __restrict__ Uf, const float* __restrict__ bf,
    const float* __restrict__ Wb, const float* __restrict__ Ub, const float* __restrict__ bb,
    char* __restrict__ fbuf, char* __restrict__ bbuf)
{
    const int tid = blockIdx.x*64 + threadIdx.x;
    const int q   = tid & 7;
    const int e   = tid >> 3;
    const int b   = e & (NB-1);
    const int dir = e >> 13;
    const int g   = q & 3;
    const int m   = q >> 2;

    const float* W  = dir ? Wb : Wf;
    const float* U  = dir ? Ub : Uf;
    const float* bi = dir ? bb : bf;

    const float cE = (g==2) ? -2.88539008177792681f : -1.44269504088896341f;
    const float cM = (g==2) ? 2.0f : 1.0f;
    const float cB = (g==2) ? -1.0f : 0.0f;

    f32x2 Wx2[3][3], Uh2[3][3];
    float cEb[3];
#pragma unroll
    for (int i=0;i<3;++i){
        const int r = g*6 + 3*m + i;
#pragma unroll
        for (int k=0;k<3;++k) Wx2[i][k] = f32x2{W[r*6+2*k], W[r*6+2*k+1]};
        Uh2[i][0] = f32x2{U[r*6+3*m+0],     U[r*6+3*m+1]};
        Uh2[i][1] = f32x2{U[r*6+3*m+2],     U[r*6+3*(1-m)+0]};
        Uh2[i][2] = f32x2{U[r*6+3*(1-m)+1], U[r*6+3*(1-m)+2]};
        cEb[i] = cE * bi[r];
    }
#pragma unroll
    for (int i=0;i<3;++i){
#pragma unroll
        for (int k=0;k<3;++k){ PINF(Wx2[i][k]); PINF(Uh2[i][k]); }
        PINF(cEb[i]);
    }

    float ho[3], hx[3], cc[3];
    {
        const int base = dir*(NB*6) + b*6;
#pragma unroll
        for (int i=0;i<3;++i){
            ho[i] = h0[base+3*m+i];
            hx[i] = h0[base+3*(1-m)+i];
            cc[i] = c0[base+3*m+i];
        }
    }

    const float* xb = x + (size_t)b*(NT*6);
    const int dt = dir ? -1 : 1;
    int t = dir ? (NT-1) : 0;

    const size_t tstr = (size_t)NB*12;
    char* op = (dir ? bbuf : fbuf) + (size_t)b*12 + (size_t)t*tstr;
    const ptrdiff_t dop = (ptrdiff_t)dt * (ptrdiff_t)tstr;

    f32x2 xA[3], xB[3];
    auto ldx = [&](int tt, f32x2* d){
        const f32x2* p = (const f32x2*)(xb + tt*6);
        d[0]=p[0]; d[1]=p[1]; d[2]=p[2];
    };
    ldx(t, xA); ldx(t+dt, xB);

    auto STEP = [&](f32x2* xv){
        f32x2 h2_0{ho[0],ho[1]}, h2_1{ho[2],hx[0]}, h2_2{hx[1],hx[2]};
        float a[3];
#pragma unroll
        for (int i=0;i<3;++i){
            f32x2 acc = pkmul(Wx2[i][0], xv[0]);
            pkfma(acc, Wx2[i][1], xv[1]);
            pkfma(acc, Wx2[i][2], xv[2]);
            pkfma(acc, Uh2[i][0], h2_0);
            pkfma(acc, Uh2[i][1], h2_1);
            pkfma(acc, Uh2[i][2], h2_2);
            const float s = acc.x + acc.y;
            const float arg = fmaf(cE, s, cEb[i]);
            a[i] = fmaf(cM, rcp_(1.0f + exp2_(arg)), cB);
        }
        cell_update(a, cc, ho, g);
#pragma unroll
        for (int i=0;i<3;++i) hx[i] = swz4(ho[i]);
        if (g == 0){
            auto p01 = __builtin_amdgcn_cvt_pkrtz(ho[0], ho[1]);
            *(u32*)(op + 4*m) = __builtin_bit_cast(u32, p01);
            _Float16 h2v = (_Float16)ho[2];
            *(u16*)(op + 8 + 2*m) = __builtin_bit_cast(u16, h2v);
        }
    };

    for (int s=0; s<NT; s+=2){
        STEP(xA);
        { int tp = t + 2*dt; tp = tp<0?0:(tp>NT-1?NT-1:tp); ldx(tp, xA); }
        t += dt; op += dop;
        STEP(xB);
        { int tp = t + 2*dt; tp = tp<0?0:(tp>NT-1?NT-1:tp); ldx(tp, xB); }
        t += dt; op += dop;
    }
}

// ---------------------------------------------------------------------------
// Layer 1 forward scan (fp16 inputs consumed directly via v_dot2_f32_f16),
// + single r1 step + FC head. 1024 waves = 1/SIMD; pin occupancy (1,1).
// ---------------------------------------------------------------------------
__global__ __launch_bounds__(64)
__attribute__((amdgpu_waves_per_eu(1,1)))
void lstm_l1_g8(
    const char* __restrict__ fbuf, const char* __restrict__ bbuf,
    const float* __restrict__ h0, const float* __restrict__ c0,
    const float* __restrict__ W1f, const float* __restrict__ U1f, const float* __restrict__ b1f,
    const float* __restrict__ W1b, const float* __restrict__ U1b, const float* __restrict__ b1b,
    const float* __restrict__ fcw, const float* __restrict__ fcb,
    float* __restrict__ out)
{
    const int tid = blockIdx.x*64 + threadIdx.x;
    const int q = tid & 7;
    const int b = tid >> 3;
    const int g = q & 3;
    const int m = q >> 2;

    const float cE = (g==2) ? -2.88539008177792681f : -1.44269504088896341f;
    const float cM = (g==2) ? 2.0f : 1.0f;
    const float cB = (g==2) ? -1.0f : 0.0f;

    // fp16 weight pairs ordered to match the stored dwords:
    // fwd dwords: (c0,c1),(c3,c4),(c2,c5); bwd dwords: (c6,c7),(c9,c10),(c8,c11)
    h16x2 wh[3][6];
    f32x2 Uh2[3][3];
    float cEb[3];
#pragma unroll
    for (int i=0;i<3;++i){
        const int r = g*6 + 3*m + i;
        const float* Wr = W1f + r*12;
#pragma unroll
        for (int k=0;k<6;++k){
            const int c0i = (k==0)?0:(k==1)?3:(k==2)?2:(k==3)?6:(k==4)?9:8;
            const int c1i = (k==0)?1:(k==1)?4:(k==2)?5:(k==3)?7:(k==4)?10:11;
            h16x2 v; v.x = (_Float16)Wr[c0i]; v.y = (_Float16)Wr[c1i];
            wh[i][k] = v;
        }
        Uh2[i][0] = f32x2{U1f[r*6+3*m+0],     U1f[r*6+3*m+1]};
        Uh2[i][1] = f32x2{U1f[r*6+3*m+2],     U1f[r*6+3*(1-m)+0]};
        Uh2[i][2] = f32x2{U1f[r*6+3*(1-m)+1], U1f[r*6+3*(1-m)+2]};
        cEb[i] = cE * b1f[r];
    }
#pragma unroll
    for (int i=0;i<3;++i){
#pragma unroll
        for (int k=0;k<6;++k) PINF(wh[i][k]);
#pragma unroll
        for (int k=0;k<3;++k) PINF(Uh2[i][k]);
        PINF(cEb[i]);
    }

    float ho[3], hx[3], cc[3];
    {
        const int base = 2*(NB*6) + b*6;
#pragma unroll
        for (int i=0;i<3;++i){
            ho[i] = h0[base+3*m+i];
            hx[i] = h0[base+3*(1-m)+i];
            cc[i] = c0[base+3*m+i];
        }
    }

    const char* pf = fbuf + (size_t)b*12;
    const char* pb = bbuf + (size_t)b*12;
    const size_t tstr = (size_t)NB*12;

    u32 dA[6], dB[6];
    auto loadD = [&](int tt, u32* d){
        const u32* f = (const u32*)(pf + (size_t)tt*tstr);
        const u32* r = (const u32*)(pb + (size_t)tt*tstr);
        d[0]=f[0]; d[1]=f[1]; d[2]=f[2]; d[3]=r[0]; d[4]=r[1]; d[5]=r[2];
    };

    auto STEP = [&](u32* d){
        f32x2 h2_0{ho[0],ho[1]}, h2_1{ho[2],hx[0]}, h2_2{hx[1],hx[2]};
        float a[3];
#pragma unroll
        for (int i=0;i<3;++i){
            float s = dot2f(wh[i][0], __builtin_bit_cast(h16x2, d[0]), 0.0f);
#pragma unroll
            for (int k=1;k<6;++k)
                s = dot2f(wh[i][k], __builtin_bit_cast(h16x2, d[k]), s);
            f32x2 acc = pkmul(Uh2[i][0], h2_0);
            pkfma(acc, Uh2[i][1], h2_1);
            pkfma(acc, Uh2[i][2], h2_2);
            const float z = s + acc.x + acc.y;
            const float arg = fmaf(cE, z, cEb[i]);
            a[i] = fmaf(cM, rcp_(1.0f + exp2_(arg)), cB);
        }
        cell_update(a, cc, ho, g);
#pragma unroll
        for (int i=0;i<3;++i) hx[i] = swz4(ho[i]);
    };

    loadD(0, dA); loadD(1, dB);
    for (int t=0; t<NT; t+=2){
        STEP(dA);
        { int tp = t+2; tp = tp>NT-1?NT-1:tp; loadD(tp, dA); }
        STEP(dB);
        { int tp = t+3; tp = tp>NT-1?NT-1:tp; loadD(tp, dB); }
    }
    // dB holds l0[NT-1]; (ho,hx) == f1[NT-1]

    float in[12];
    in[0]=upk_lo(dB[0]); in[1]=upk_hi(dB[0]); in[3]=upk_lo(dB[1]);
    in[4]=upk_hi(dB[1]); in[2]=upk_lo(dB[2]); in[5]=upk_hi(dB[2]);
    in[6]=upk_lo(dB[3]); in[7]=upk_hi(dB[3]); in[9]=upk_lo(dB[4]);
    in[10]=upk_hi(dB[4]); in[8]=upk_lo(dB[5]); in[11]=upk_hi(dB[5]);

    // ---- r1: single reverse-direction step at t = NT-1 ----
    const int base3 = 3*(NB*6) + b*6;
    float hr[6];
#pragma unroll
    for (int j=0;j<6;++j) hr[j] = h0[base3 + j];
    float cr[3];
#pragma unroll
    for (int i=0;i<3;++i) cr[i] = c0[base3 + 3*m + i];

    float a[3];
#pragma unroll
    for (int i=0;i<3;++i){
        const int r = g*6 + 3*m + i;
        float acc = b1b[r];
#pragma unroll
        for (int k=0;k<12;++k) acc = fmaf(W1b[r*12+k], in[k], acc);
#pragma unroll
        for (int j=0;j<6;++j)  acc = fmaf(U1b[r*6+j], hr[j], acc);
        a[i] = fmaf(cM, rcp_(1.0f + exp2_(cE*acc)), cB);
    }
    float r1o[3];
    cell_update(a, cr, r1o, g);
    float r1x[3];
#pragma unroll
    for (int i=0;i<3;++i) r1x[i] = swz4(r1o[i]);

    // ---- head ----
    if (g == 0){
#pragma unroll
        for (int i=0;i<3;++i){
            const int r = 3*m + i;
            float acc = fcb[r];
#pragma unroll
            for (int k=0;k<3;++k){
                acc = fmaf(fcw[r*12 + 3*m + k],         fmaxf(ho[k],0.f), acc);
                acc = fmaf(fcw[r*12 + 3*(1-m) + k],     fmaxf(hx[k],0.f), acc);
                acc = fmaf(fcw[r*12 + 6 + 3*m + k],     fmaxf(r1o[k],0.f), acc);
                acc = fmaf(fcw[r*12 + 6 + 3*(1-m) + k], fmaxf(r1x[k],0.f), acc);
            }
            out[b*6 + r] = acc;
        }
    }
}

extern "C" void kernel_launch(void* const* d_in, const int* in_sizes, int n_in,
                              void* d_out, int out_size, void* d_ws, size_t ws_size,
                              hipStream_t stream)
{
    (void)in_sizes; (void)n_in; (void)out_size; (void)ws_size;
    const float* x    = (const float*)d_in[0];
    const float* h0   = (const float*)d_in[1];
    const float* c0   = (const float*)d_in[2];
    const float* W0f  = (const float*)d_in[3];
    const float* U0f  = (const float*)d_in[4];
    const float* b0f  = (const float*)d_in[5];
    const float* W0b  = (const float*)d_in[6];
    const float* U0b  = (const float*)d_in[7];
    const float* b0b  = (const float*)d_in[8];
    const float* W1f  = (const float*)d_in[9];
    const float* U1f  = (const float*)d_in[10];
    const float* b1f  = (const float*)d_in[11];
    const float* W1b  = (const float*)d_in[12];
    const float* U1b  = (const float*)d_in[13];
    const float* b1b  = (const float*)d_in[14];
    const float* fcw  = (const float*)d_in[15];
    const float* fcb  = (const float*)d_in[16];
    float* out = (float*)d_out;
    char* ws = (char*)d_ws;

    char* fbuf = ws;
    char* bbuf = ws + (size_t)NT*NB*12;

    lstm_l0_g8<<<dim3(2048), dim3(64), 0, stream>>>(x, h0, c0, W0f, U0f, b0f, W0b, U0b, b0b, fbuf, bbuf);
    lstm_l1_g8<<<dim3(1024), dim3(64), 0, stream>>>(fbuf, bbuf, h0, c0, W1f, U1f, b1f, W1b, U1b, b1b, fcw, fcb, out);
}